// Round 3
// baseline (390.946 us; speedup 1.0000x reference)
//
#include <hip/hip_runtime.h>
#include <stdint.h>

typedef unsigned long long u64;
typedef float v2 __attribute__((ext_vector_type(2)));

#define THRESH_F 5e-5f
#define BB 128
#define HH 384
#define WW_ 384
#define WPR 6                        // u64 words per 384-pixel row
#define IMG_WORDS (HH*WPR)           // 2304
#define OH 378
#define OW 378
#define COVN (49.0f/48.0f)

#define HALF_ROWS 192
#define HALO 30
#define NROWS_M (HALF_ROWS + HALO)   // 222 (every block touches one image edge)
#define NW_M (NROWS_M * WPR)         // 1332
#define OUTW_M (HALF_ROWS * WPR)     // 1152

// div by 6 via magic, valid for w < 131072
__device__ __forceinline__ int div6(int w) { return (w * 43691) >> 18; }

// ---- K1: fused binarize + full morphology chain, 2 blocks per image -------
// binarize -> erode3 -> dilate_h15 -> dilate_v15 -> erode_h14 -> erode_v14
// Block handles output rows [r0, r0+192); LDS window of 222 rows covers the
// 30-row halo chain depth (1 + 15 + 14). Window edge == image edge on one
// side (clamping correct); on the halo side garbage never propagates into
// the output rows (consumers stay >=1 row inside the window).
__global__ void __launch_bounds__(256) k_morph(const float* __restrict__ Y,
                                               u64* __restrict__ gout_all,
                                               float* __restrict__ accum) {
    __shared__ u64 A[NW_M];
    __shared__ u64 Bf[NW_M];
    const int blk = blockIdx.x;
    const int b = blk >> 1;
    const int half = blk & 1;
    const int r0 = half * HALF_ROWS;
    const int lo = half ? (HH - NROWS_M) : 0;   // 162 or 0
    const int t = threadIdx.x;

    if (blk == 0) {                 // zero the accum slots (k_ssim runs later)
        for (int i = t; i < 1024; i += 256) accum[i] = 0.f;
    }

    // ---- binarize rows [lo, lo+222) into bit LDS A ----
    const int lane = t & 63;
    const int wv = t >> 6;
    const float* Yb = Y + (size_t)b * (HH * WW_);
    for (int wi = wv; wi < NW_M; wi += 4) {
        int lrow = div6(wi);
        int ww = wi - lrow * 6;
        float y = Yb[(size_t)(lo + lrow) * WW_ + ww * 64 + lane];
        u64 bal = __ballot(y > THRESH_F);
        if (lane == 0) A[wi] = bal;
    }
    __syncthreads();

    // ---- erode3: A -> Bf (OOB = 1) ----
    for (int w = t; w < NW_M; w += 256) {
        int row = div6(w);
        int ww = w - row * 6;
        int rlo = row > 0 ? row - 1 : row;
        int rhi = row < NROWS_M - 1 ? row + 1 : row;
        u64 res = ~0ull;
        for (int rr = rlo; rr <= rhi; ++rr) {
            const u64* rp = &A[rr * 6];
            u64 a = ww > 0 ? rp[ww - 1] : 0ull;
            u64 bb = rp[ww];
            u64 c = ww < 5 ? rp[ww + 1] : 0ull;
            u64 l  = (bb << 1) | (ww > 0 ? (a >> 63) : 1ull);
            u64 r2 = (bb >> 1) | (ww < 5 ? (c << 63) : (1ull << 63));
            res &= bb & l & r2;
        }
        Bf[w] = res;
    }
    __syncthreads();

    // ---- dilate_h15: Bf -> A (OOB = 0) ----
    for (int w = t; w < NW_M; w += 256) {
        int row = div6(w);
        int ww = w - row * 6;
        const u64* rp = &Bf[row * 6];
        u64 a = ww > 0 ? rp[ww - 1] : 0ull;
        u64 bb = rp[ww];
        u64 c = ww < 5 ? rp[ww + 1] : 0ull;
        __uint128_t X = (((__uint128_t)bb) << 64) | a;
        X |= X << 1; X |= X << 2; X |= X << 4; X |= X << 8;
        __uint128_t Z = (((__uint128_t)c) << 64) | bb;
        Z |= Z >> 1; Z |= Z >> 2; Z |= Z >> 4; Z |= Z >> 8;
        A[w] = (u64)(X >> 64) | (u64)Z;
    }
    __syncthreads();

    // ---- dilate_v15: A -> Bf ----
    for (int w = t; w < NW_M; w += 256) {
        int row = div6(w);
        int ww = w - row * 6;
        int lo2 = row - 15 < 0 ? 0 : row - 15;
        int hi2 = row + 15 > NROWS_M - 1 ? NROWS_M - 1 : row + 15;
        u64 acc = 0ull;
        for (int rr = lo2; rr <= hi2; ++rr) acc |= A[rr * 6 + ww];
        Bf[w] = acc;
    }
    __syncthreads();

    // ---- erode_h14: Bf -> A (complement-dilate, OOB = 1) ----
    for (int w = t; w < NW_M; w += 256) {
        int row = div6(w);
        int ww = w - row * 6;
        const u64* rp = &Bf[row * 6];
        u64 a = ww > 0 ? rp[ww - 1] : ~0ull;
        u64 bb = rp[ww];
        u64 c = ww < 5 ? rp[ww + 1] : ~0ull;
        u64 na = ~a, nb = ~bb, nc = ~c;
        __uint128_t X = (((__uint128_t)nb) << 64) | na;
        X |= X << 1; X |= X << 2; X |= X << 4; X |= X << 7;
        __uint128_t Z = (((__uint128_t)nc) << 64) | nb;
        Z |= Z >> 1; Z |= Z >> 2; Z |= Z >> 4; Z |= Z >> 7;
        A[w] = ~((u64)(X >> 64) | (u64)Z);
    }
    __syncthreads();

    // ---- erode_v14: A -> global, rows [r0, r0+192) ----
    u64* gout = gout_all + (size_t)b * IMG_WORDS;
    for (int w = t; w < OUTW_M; w += 256) {
        int lrow = div6(w);
        int ww = w - lrow * 6;
        int lr = (r0 + lrow) - lo;
        int lo2 = lr - 14 < 0 ? 0 : lr - 14;
        int hi2 = lr + 14 > NROWS_M - 1 ? NROWS_M - 1 : lr + 14;
        u64 acc = ~0ull;
        for (int rr = lo2; rr <= hi2; ++rr) acc &= A[rr * 6 + ww];
        gout[(size_t)(r0 + lrow) * WPR + ww] = acc;
    }
}

// ---- K2: fused masked SSIM, CW=2, 16-row chunks for occupancy -------------
// grid (3, 6, 128), block 256: 64 pairs x 4 chunk-slots. 2304 blocks =
// 9 waves/SIMD demanded (VGPR-capped at 5) vs round-2's 4.5.
__global__ void __launch_bounds__(256) k_ssim(
    const float* __restrict__ Xg, const float* __restrict__ Yg,
    const float* __restrict__ drg, const u64* __restrict__ Mg,
    float* __restrict__ accum)
{
    const int tx = threadIdx.x & 63;
    const int cz = threadIdx.x >> 6;
    const int p  = blockIdx.x * 64 + tx;              // pair index
    const int chunk = blockIdx.y * 4 + cz;            // 0..23 (uniform per wave)
    const int b  = blockIdx.z;

    float lsum = 0.0f;
    if (p < 189) {
        const int j  = p * 2;
        const int i0 = chunk * 16;
        const int i1 = (i0 + 16 < OH) ? (i0 + 16) : OH;
        const int nrows = (i1 - i0) + 6;              // 22 or 16, wave-uniform
        const float drv = drg[b];
        const float C1q = 1e-4f * drv * drv * 2401.0f;    // C1*49^2
        const float C2q = 9e-4f * drv * drv * 2401.0f;    // C2*49^2
        const float* Xp = Xg + (size_t)b * HH * WW_ + (size_t)i0 * WW_ + j;
        const float* Yp = Yg + (size_t)b * HH * WW_ + (size_t)i0 * WW_ + j;
        const int w0i = j >> 6;
        const int w1i = (w0i < WPR - 1) ? (w0i + 1) : w0i;
        const int sh  = j & 63;
        const u64* Mp = Mg + (size_t)b * HH * WPR + (size_t)i0 * WPR;

        v2 ring0[7], ring1[7], ring2[7], ring3[7], ring4[7];
        #pragma unroll
        for (int t = 0; t < 7; ++t) {
            ring0[t] = 0.f; ring1[t] = 0.f; ring2[t] = 0.f; ring3[t] = 0.f; ring4[t] = 0.f;
        }
        v2 s0 = 0.f, s1 = 0.f, s2 = 0.f, s3 = 0.f, s4 = 0.f;

        for (int base = 0; base < 22; base += 7) {
            if (base >= nrows) break;                 // uniform
            #pragma unroll
            for (int ph = 0; ph < 7; ++ph) {
                const int rr = base + ph;
                if (rr >= nrows) break;               // uniform
                const float* xr = Xp + rr * WW_;
                const float* yr = Yp + rr * WW_;
                v2 xa = *(const v2*)(xr);     v2 xb = *(const v2*)(xr + 2);
                v2 xc = *(const v2*)(xr + 4); v2 xd = *(const v2*)(xr + 6);
                v2 ya = *(const v2*)(yr);     v2 yb = *(const v2*)(yr + 2);
                v2 yc = *(const v2*)(yr + 4); v2 yd = *(const v2*)(yr + 6);

                const u64* mrow = Mp + rr * WPR;
                u64 mw0 = mrow[w0i];
                u64 mw1 = mrow[w1i];
                unsigned win8 = ((unsigned)(mw0 >> sh) |
                                 (unsigned)((mw1 << 1) << (63 - sh))) & 0xFFu;

                if (__builtin_expect(__any(win8 != 0xFFu), 0)) {
                    float m0 = (float)( win8       & 1u);
                    float m1 = (float)((win8 >> 1) & 1u);
                    float m2 = (float)((win8 >> 2) & 1u);
                    float m3 = (float)((win8 >> 3) & 1u);
                    float m4 = (float)((win8 >> 4) & 1u);
                    float m5 = (float)((win8 >> 5) & 1u);
                    float m6 = (float)((win8 >> 6) & 1u);
                    float m7 = (float)((win8 >> 7) & 1u);
                    xa.x *= m0; xa.y *= m1; xb.x *= m2; xb.y *= m3;
                    xc.x *= m4; xc.y *= m5; xd.x *= m6; xd.y *= m7;
                    ya.x *= m0; ya.y *= m1; yb.x *= m2; yb.y *= m3;
                    yc.x *= m4; yc.y *= m5; yd.x *= m6; yd.y *= m7;
                }

                v2 xxa = xa * xa, xxb = xb * xb, xxc = xc * xc, xxd = xd * xd;
                v2 yya = ya * ya, yyb = yb * yb, yyc = yc * yc, yyd = yd * yd;
                v2 xya = xa * ya, xyb = xb * yb, xyc = xc * yc, xyd = xd * yd;

                float h;
                h = ((xa.x + xa.y) + (xb.x + xb.y)) + ((xc.x + xc.y) + xd.x);
                v2 hX  = { h, h + xd.y - xa.x };
                h = ((ya.x + ya.y) + (yb.x + yb.y)) + ((yc.x + yc.y) + yd.x);
                v2 hY  = { h, h + yd.y - ya.x };
                h = ((xxa.x + xxa.y) + (xxb.x + xxb.y)) + ((xxc.x + xxc.y) + xxd.x);
                v2 hXX = { h, h + xxd.y - xxa.x };
                h = ((yya.x + yya.y) + (yyb.x + yyb.y)) + ((yyc.x + yyc.y) + yyd.x);
                v2 hYY = { h, h + yyd.y - yya.x };
                h = ((xya.x + xya.y) + (xyb.x + xyb.y)) + ((xyc.x + xyc.y) + xyd.x);
                v2 hXY = { h, h + xyd.y - xya.x };

                v2 o;
                o = ring0[ph]; ring0[ph] = hX;  s0 += hX  - o;
                o = ring1[ph]; ring1[ph] = hY;  s1 += hY  - o;
                o = ring2[ph]; ring2[ph] = hXX; s2 += hXX - o;
                o = ring3[ph]; ring3[ph] = hYY; s3 += hYY - o;
                o = ring4[ph]; ring4[ph] = hXY; s4 += hXY - o;

                if (rr >= 6) {
                    v2 t3  = s0 * s1;
                    v2 t12 = s1 * s1 + s0 * s0;
                    v2 A1  = 2.0f * t3 + C1q;
                    v2 u   = 49.0f * s4 - t3;
                    v2 A2  = (2.0f * COVN) * u + C2q;
                    v2 B1  = t12 + C1q;
                    v2 w   = s2 + s3;
                    v2 vsum = 49.0f * w - t12;
                    v2 B2  = COVN * vsum + C2q;
                    v2 num = A1 * A2;
                    v2 den = B1 * B2;
                    float r0 = __builtin_amdgcn_rcpf(den.x);
                    float r1 = __builtin_amdgcn_rcpf(den.y);
                    lsum += num.x * r0 + num.y * r1;
                }
            }
        }
    }

    __shared__ float sm[256];
    sm[threadIdx.x] = lsum;
    __syncthreads();
    #pragma unroll
    for (int off = 128; off > 0; off >>= 1) {
        if (threadIdx.x < off) sm[threadIdx.x] += sm[threadIdx.x + off];
        __syncthreads();
    }
    if (threadIdx.x == 0) {
        int flat = (blockIdx.z * 6 + blockIdx.y) * 3 + blockIdx.x;
        atomicAdd(&accum[flat & 1023], sm[0]);
    }
}

// ---- K3: finalize -> 1 - sum/N (double accumulate) ------------------------
__global__ void k_final(const float* __restrict__ accum, float* __restrict__ out) {
    __shared__ double sm[256];
    double v = 0.0;
    for (int i = threadIdx.x; i < 1024; i += 256) v += (double)accum[i];
    sm[threadIdx.x] = v;
    __syncthreads();
    #pragma unroll
    for (int off = 128; off > 0; off >>= 1) {
        if (threadIdx.x < off) sm[threadIdx.x] += sm[threadIdx.x + off];
        __syncthreads();
    }
    if (threadIdx.x == 0) {
        out[0] = (float)(1.0 - sm[0] / 18289152.0);   // N = 128*378*378
    }
}

extern "C" void kernel_launch(void* const* d_in, const int* in_sizes, int n_in,
                              void* d_out, int out_size, void* d_ws, size_t ws_size,
                              hipStream_t stream) {
    const float* X  = (const float*)d_in[0];
    const float* Y  = (const float*)d_in[1];
    const float* dr = (const float*)d_in[2];
    float* out = (float*)d_out;

    char* ws = (char*)d_ws;
    float* accum = (float*)ws;                        // 4 KB
    u64* maskB = (u64*)(ws + 4096);                   // 2.36 MB bit mask

    k_morph<<<BB * 2, 256, 0, stream>>>(Y, maskB, accum);
    dim3 g(3, 6, 128);
    k_ssim<<<g, 256, 0, stream>>>(X, Y, dr, maskB, accum);
    k_final<<<1, 256, 0, stream>>>(accum, out);
}

// Round 4
// 267.376 us; speedup vs baseline: 1.4622x; 1.4622x over previous
//
#include <hip/hip_runtime.h>
#include <stdint.h>

typedef unsigned long long u64;
typedef float v2 __attribute__((ext_vector_type(2)));

#define THRESH_F 5e-5f
#define BB 128
#define HH 384
#define WW_ 384
#define WPR 6                        // u64 words per 384-pixel row
#define IMG_WORDS (HH*WPR)           // 2304
#define OH 378
#define OW 378
#define PIX (BB*HH*WW_)              // 18874368
#define COVN (49.0f/48.0f)

#define SLAB 48                      // output rows per morph block
#define HALO 30                      // morphology chain depth: 1 + 15 + 14
#define MAXROWS (SLAB + 2*HALO)      // 108
#define MAXW (MAXROWS * WPR)         // 648

// div by 6 via magic, valid for w < 131072
__device__ __forceinline__ int div6(int w) { return (w * 43691) >> 18; }

// ---- K1: binarize Y -> bit buffer (wave ballot, fully parallel) -----------
__global__ void k_binarize(const float* __restrict__ Y, u64* __restrict__ bits,
                           float* __restrict__ accum) {
    if (blockIdx.x == 0) {           // zero accum slots (consumed by k_ssim later)
        for (int i = threadIdx.x; i < 1024; i += 256) accum[i] = 0.f;
    }
    int idx = blockIdx.x * 256 + threadIdx.x;         // grid exact: PIX/256
    float y = Y[idx];
    u64 bal = __ballot(y > THRESH_F);
    if ((threadIdx.x & 63) == 0) bits[idx >> 6] = bal;
}

// ---- K2: fused morphology on bits, 8 slabs per image (1024 blocks) --------
// erode3 -> dilate_h15 -> dilate_v15 -> erode_h14 -> erode_v14, LDS-resident.
// Window = output slab +/- 30 rows (clamped at image edges). Garbage at
// interior window edges provably never propagates into output rows.
__global__ void __launch_bounds__(256) k_morph(const u64* __restrict__ gbits,
                                               u64* __restrict__ gout_all) {
    __shared__ u64 A[MAXW];
    __shared__ u64 Bf[MAXW];
    const int blk = blockIdx.x;
    const int b = blk >> 3;
    const int slab = blk & 7;
    const int r0 = slab * SLAB;
    const int w0row = (r0 - HALO < 0) ? 0 : r0 - HALO;
    int w1row = r0 + SLAB + HALO; if (w1row > HH) w1row = HH;
    const int nrows = w1row - w0row;                  // 78 or 108
    const int NW = nrows * WPR;
    const int t = threadIdx.x;

    const u64* gin = gbits + (size_t)b * IMG_WORDS + (size_t)w0row * WPR;
    for (int w = t; w < NW; w += 256) A[w] = gin[w];
    __syncthreads();

    // ---- erode3: A -> Bf (OOB = 1 for erosion) ----
    for (int w = t; w < NW; w += 256) {
        int row = div6(w);
        int ww = w - row * 6;
        int rlo = row > 0 ? row - 1 : row;
        int rhi = row < nrows - 1 ? row + 1 : row;
        u64 res = ~0ull;
        for (int rr = rlo; rr <= rhi; ++rr) {
            const u64* rp = &A[rr * 6];
            u64 a = ww > 0 ? rp[ww - 1] : 0ull;
            u64 bb = rp[ww];
            u64 c = ww < 5 ? rp[ww + 1] : 0ull;
            u64 l  = (bb << 1) | (ww > 0 ? (a >> 63) : 1ull);
            u64 r2 = (bb >> 1) | (ww < 5 ? (c << 63) : (1ull << 63));
            res &= bb & l & r2;
        }
        Bf[w] = res;
    }
    __syncthreads();

    // ---- dilate_h15: Bf -> A (OOB = 0) ----
    for (int w = t; w < NW; w += 256) {
        int row = div6(w);
        int ww = w - row * 6;
        const u64* rp = &Bf[row * 6];
        u64 a = ww > 0 ? rp[ww - 1] : 0ull;
        u64 bb = rp[ww];
        u64 c = ww < 5 ? rp[ww + 1] : 0ull;
        __uint128_t X = (((__uint128_t)bb) << 64) | a;
        X |= X << 1; X |= X << 2; X |= X << 4; X |= X << 8;
        __uint128_t Z = (((__uint128_t)c) << 64) | bb;
        Z |= Z >> 1; Z |= Z >> 2; Z |= Z >> 4; Z |= Z >> 8;
        A[w] = (u64)(X >> 64) | (u64)Z;
    }
    __syncthreads();

    // ---- dilate_v15: A -> Bf ----
    for (int w = t; w < NW; w += 256) {
        int row = div6(w);
        int ww = w - row * 6;
        int lo2 = row - 15 < 0 ? 0 : row - 15;
        int hi2 = row + 15 > nrows - 1 ? nrows - 1 : row + 15;
        u64 acc = 0ull;
        for (int rr = lo2; rr <= hi2; ++rr) acc |= A[rr * 6 + ww];
        Bf[w] = acc;
    }
    __syncthreads();

    // ---- erode_h14: Bf -> A (complement-dilate, OOB = 1) ----
    for (int w = t; w < NW; w += 256) {
        int row = div6(w);
        int ww = w - row * 6;
        const u64* rp = &Bf[row * 6];
        u64 a = ww > 0 ? rp[ww - 1] : ~0ull;
        u64 bb = rp[ww];
        u64 c = ww < 5 ? rp[ww + 1] : ~0ull;
        u64 na = ~a, nb = ~bb, nc = ~c;
        __uint128_t X = (((__uint128_t)nb) << 64) | na;
        X |= X << 1; X |= X << 2; X |= X << 4; X |= X << 7;
        __uint128_t Z = (((__uint128_t)nc) << 64) | nb;
        Z |= Z >> 1; Z |= Z >> 2; Z |= Z >> 4; Z |= Z >> 7;
        A[w] = ~((u64)(X >> 64) | (u64)Z);
    }
    __syncthreads();

    // ---- erode_v14: A -> global, output rows [r0, r0+48) ----
    u64* gout = gout_all + (size_t)b * IMG_WORDS;
    const int base = r0 - w0row;
    for (int w = t; w < SLAB * WPR; w += 256) {
        int lrow = div6(w);
        int ww = w - lrow * 6;
        int lr = base + lrow;
        int lo2 = lr - 14 < 0 ? 0 : lr - 14;
        int hi2 = lr + 14 > nrows - 1 ? nrows - 1 : lr + 14;
        u64 acc = ~0ull;
        for (int rr = lo2; rr <= hi2; ++rr) acc &= A[rr * 6 + ww];
        gout[(size_t)(r0 + lrow) * WPR + ww] = acc;
    }
}

// ---- K3: fused masked SSIM, CW=2, 16-row chunks ---------------------------
__global__ void __launch_bounds__(256) k_ssim(
    const float* __restrict__ Xg, const float* __restrict__ Yg,
    const float* __restrict__ drg, const u64* __restrict__ Mg,
    float* __restrict__ accum)
{
    const int tx = threadIdx.x & 63;
    const int cz = threadIdx.x >> 6;
    const int p  = blockIdx.x * 64 + tx;              // pair index
    const int chunk = blockIdx.y * 4 + cz;            // 0..23 (uniform per wave)
    const int b  = blockIdx.z;

    float lsum = 0.0f;
    if (p < 189) {
        const int j  = p * 2;
        const int i0 = chunk * 16;
        const int i1 = (i0 + 16 < OH) ? (i0 + 16) : OH;
        const int nrows = (i1 - i0) + 6;              // 22 or 16, wave-uniform
        const float drv = drg[b];
        const float C1q = 1e-4f * drv * drv * 2401.0f;    // C1*49^2
        const float C2q = 9e-4f * drv * drv * 2401.0f;    // C2*49^2
        const float* Xp = Xg + (size_t)b * HH * WW_ + (size_t)i0 * WW_ + j;
        const float* Yp = Yg + (size_t)b * HH * WW_ + (size_t)i0 * WW_ + j;
        const int w0i = j >> 6;
        const int w1i = (w0i < WPR - 1) ? (w0i + 1) : w0i;
        const int sh  = j & 63;
        const u64* Mp = Mg + (size_t)b * HH * WPR + (size_t)i0 * WPR;

        v2 ring0[7], ring1[7], ring2[7], ring3[7], ring4[7];
        #pragma unroll
        for (int t = 0; t < 7; ++t) {
            ring0[t] = 0.f; ring1[t] = 0.f; ring2[t] = 0.f; ring3[t] = 0.f; ring4[t] = 0.f;
        }
        v2 s0 = 0.f, s1 = 0.f, s2 = 0.f, s3 = 0.f, s4 = 0.f;

        for (int base = 0; base < 22; base += 7) {
            if (base >= nrows) break;                 // uniform
            #pragma unroll
            for (int ph = 0; ph < 7; ++ph) {
                const int rr = base + ph;
                if (rr >= nrows) break;               // uniform
                const float* xr = Xp + rr * WW_;
                const float* yr = Yp + rr * WW_;
                v2 xa = *(const v2*)(xr);     v2 xb = *(const v2*)(xr + 2);
                v2 xc = *(const v2*)(xr + 4); v2 xd = *(const v2*)(xr + 6);
                v2 ya = *(const v2*)(yr);     v2 yb = *(const v2*)(yr + 2);
                v2 yc = *(const v2*)(yr + 4); v2 yd = *(const v2*)(yr + 6);

                const u64* mrow = Mp + rr * WPR;
                u64 mw0 = mrow[w0i];
                u64 mw1 = mrow[w1i];
                unsigned win8 = ((unsigned)(mw0 >> sh) |
                                 (unsigned)((mw1 << 1) << (63 - sh))) & 0xFFu;

                if (__builtin_expect(__any(win8 != 0xFFu), 0)) {
                    float m0 = (float)( win8       & 1u);
                    float m1 = (float)((win8 >> 1) & 1u);
                    float m2 = (float)((win8 >> 2) & 1u);
                    float m3 = (float)((win8 >> 3) & 1u);
                    float m4 = (float)((win8 >> 4) & 1u);
                    float m5 = (float)((win8 >> 5) & 1u);
                    float m6 = (float)((win8 >> 6) & 1u);
                    float m7 = (float)((win8 >> 7) & 1u);
                    xa.x *= m0; xa.y *= m1; xb.x *= m2; xb.y *= m3;
                    xc.x *= m4; xc.y *= m5; xd.x *= m6; xd.y *= m7;
                    ya.x *= m0; ya.y *= m1; yb.x *= m2; yb.y *= m3;
                    yc.x *= m4; yc.y *= m5; yd.x *= m6; yd.y *= m7;
                }

                v2 xxa = xa * xa, xxb = xb * xb, xxc = xc * xc, xxd = xd * xd;
                v2 yya = ya * ya, yyb = yb * yb, yyc = yc * yc, yyd = yd * yd;
                v2 xya = xa * ya, xyb = xb * yb, xyc = xc * yc, xyd = xd * yd;

                float h;
                h = ((xa.x + xa.y) + (xb.x + xb.y)) + ((xc.x + xc.y) + xd.x);
                v2 hX  = { h, h + xd.y - xa.x };
                h = ((ya.x + ya.y) + (yb.x + yb.y)) + ((yc.x + yc.y) + yd.x);
                v2 hY  = { h, h + yd.y - ya.x };
                h = ((xxa.x + xxa.y) + (xxb.x + xxb.y)) + ((xxc.x + xxc.y) + xxd.x);
                v2 hXX = { h, h + xxd.y - xxa.x };
                h = ((yya.x + yya.y) + (yyb.x + yyb.y)) + ((yyc.x + yyc.y) + yyd.x);
                v2 hYY = { h, h + yyd.y - yya.x };
                h = ((xya.x + xya.y) + (xyb.x + xyb.y)) + ((xyc.x + xyc.y) + xyd.x);
                v2 hXY = { h, h + xyd.y - xya.x };

                v2 o;
                o = ring0[ph]; ring0[ph] = hX;  s0 += hX  - o;
                o = ring1[ph]; ring1[ph] = hY;  s1 += hY  - o;
                o = ring2[ph]; ring2[ph] = hXX; s2 += hXX - o;
                o = ring3[ph]; ring3[ph] = hYY; s3 += hYY - o;
                o = ring4[ph]; ring4[ph] = hXY; s4 += hXY - o;

                if (rr >= 6) {
                    v2 t3  = s0 * s1;
                    v2 t12 = s1 * s1 + s0 * s0;
                    v2 A1  = 2.0f * t3 + C1q;
                    v2 u   = 49.0f * s4 - t3;
                    v2 A2  = (2.0f * COVN) * u + C2q;
                    v2 B1  = t12 + C1q;
                    v2 w   = s2 + s3;
                    v2 vsum = 49.0f * w - t12;
                    v2 B2  = COVN * vsum + C2q;
                    v2 num = A1 * A2;
                    v2 den = B1 * B2;
                    float r0 = __builtin_amdgcn_rcpf(den.x);
                    float r1 = __builtin_amdgcn_rcpf(den.y);
                    lsum += num.x * r0 + num.y * r1;
                }
            }
        }
    }

    __shared__ float sm[256];
    sm[threadIdx.x] = lsum;
    __syncthreads();
    #pragma unroll
    for (int off = 128; off > 0; off >>= 1) {
        if (threadIdx.x < off) sm[threadIdx.x] += sm[threadIdx.x + off];
        __syncthreads();
    }
    if (threadIdx.x == 0) {
        int flat = (blockIdx.z * 6 + blockIdx.y) * 3 + blockIdx.x;
        atomicAdd(&accum[flat & 1023], sm[0]);
    }
}

// ---- K4: finalize -> 1 - sum/N (double accumulate) ------------------------
__global__ void k_final(const float* __restrict__ accum, float* __restrict__ out) {
    __shared__ double sm[256];
    double v = 0.0;
    for (int i = threadIdx.x; i < 1024; i += 256) v += (double)accum[i];
    sm[threadIdx.x] = v;
    __syncthreads();
    #pragma unroll
    for (int off = 128; off > 0; off >>= 1) {
        if (threadIdx.x < off) sm[threadIdx.x] += sm[threadIdx.x + off];
        __syncthreads();
    }
    if (threadIdx.x == 0) {
        out[0] = (float)(1.0 - sm[0] / 18289152.0);   // N = 128*378*378
    }
}

extern "C" void kernel_launch(void* const* d_in, const int* in_sizes, int n_in,
                              void* d_out, int out_size, void* d_ws, size_t ws_size,
                              hipStream_t stream) {
    const float* X  = (const float*)d_in[0];
    const float* Y  = (const float*)d_in[1];
    const float* dr = (const float*)d_in[2];
    float* out = (float*)d_out;

    char* ws = (char*)d_ws;
    float* accum = (float*)ws;                        // 4 KB
    u64* bitsRaw = (u64*)(ws + 4096);                 // 2.36 MB binarized
    u64* maskB = (u64*)(ws + 4096 + (size_t)(BB * IMG_WORDS) * 8);  // 2.36 MB final mask

    k_binarize<<<PIX / 256, 256, 0, stream>>>(Y, bitsRaw, accum);
    k_morph<<<BB * 8, 256, 0, stream>>>(bitsRaw, maskB);
    dim3 g(3, 6, 128);
    k_ssim<<<g, 256, 0, stream>>>(X, Y, dr, maskB, accum);
    k_final<<<1, 256, 0, stream>>>(accum, out);
}

// Round 5
// 239.251 us; speedup vs baseline: 1.6340x; 1.1176x over previous
//
#include <hip/hip_runtime.h>
#include <stdint.h>

typedef unsigned long long u64;
typedef float v2 __attribute__((ext_vector_type(2)));

#define THRESH_F 5e-5f
#define BB 128
#define HH 384
#define WW_ 384
#define WPR 6                        // u64 words per 384-pixel row
#define IMG_WORDS (HH*WPR)           // 2304
#define OH 378
#define OW 378
#define PIX (BB*HH*WW_)              // 18874368
#define COVN (49.0f/48.0f)

#define SLAB 48                      // output rows per morph block
#define HALO 30                      // morphology chain depth: 1 + 15 + 14
#define MAXROWS (SLAB + 2*HALO)      // 108
#define MAXW (MAXROWS * WPR)         // 648

#define BIN_BLOCKS 1536              // grid-stride: 73728 WGs was dispatch-rate-bound

// div by 6 via magic, valid for w < 131072
__device__ __forceinline__ int div6(int w) { return (w * 43691) >> 18; }

// ---- K1: binarize Y -> bit buffer (grid-stride, 48 iters/thread) ----------
__global__ void __launch_bounds__(256) k_binarize(const float* __restrict__ Y,
                                                  u64* __restrict__ bits,
                                                  float* __restrict__ accum) {
    if (blockIdx.x == 0) {           // zero accum slots (consumed by k_ssim later)
        for (int i = threadIdx.x; i < 1024; i += 256) accum[i] = 0.f;
    }
    int tid = blockIdx.x * 256 + threadIdx.x;
    const int stride = BIN_BLOCKS * 256;
    #pragma unroll 4
    for (int idx = tid; idx < PIX; idx += stride) {
        float y = Y[idx];
        u64 bal = __ballot(y > THRESH_F);
        if ((threadIdx.x & 63) == 0) bits[idx >> 6] = bal;
    }
}

// ---- K2: fused morphology on bits, 8 slabs per image (1024 blocks) --------
__global__ void __launch_bounds__(256) k_morph(const u64* __restrict__ gbits,
                                               u64* __restrict__ gout_all) {
    __shared__ u64 A[MAXW];
    __shared__ u64 Bf[MAXW];
    const int blk = blockIdx.x;
    const int b = blk >> 3;
    const int slab = blk & 7;
    const int r0 = slab * SLAB;
    const int w0row = (r0 - HALO < 0) ? 0 : r0 - HALO;
    int w1row = r0 + SLAB + HALO; if (w1row > HH) w1row = HH;
    const int nrows = w1row - w0row;                  // 78 or 108
    const int NW = nrows * WPR;
    const int t = threadIdx.x;

    const u64* gin = gbits + (size_t)b * IMG_WORDS + (size_t)w0row * WPR;
    for (int w = t; w < NW; w += 256) A[w] = gin[w];
    __syncthreads();

    // ---- erode3: A -> Bf ----
    for (int w = t; w < NW; w += 256) {
        int row = div6(w);
        int ww = w - row * 6;
        int rlo = row > 0 ? row - 1 : row;
        int rhi = row < nrows - 1 ? row + 1 : row;
        u64 res = ~0ull;
        for (int rr = rlo; rr <= rhi; ++rr) {
            const u64* rp = &A[rr * 6];
            u64 a = ww > 0 ? rp[ww - 1] : 0ull;
            u64 bb = rp[ww];
            u64 c = ww < 5 ? rp[ww + 1] : 0ull;
            u64 l  = (bb << 1) | (ww > 0 ? (a >> 63) : 1ull);
            u64 r2 = (bb >> 1) | (ww < 5 ? (c << 63) : (1ull << 63));
            res &= bb & l & r2;
        }
        Bf[w] = res;
    }
    __syncthreads();

    // ---- dilate_h15: Bf -> A ----
    for (int w = t; w < NW; w += 256) {
        int row = div6(w);
        int ww = w - row * 6;
        const u64* rp = &Bf[row * 6];
        u64 a = ww > 0 ? rp[ww - 1] : 0ull;
        u64 bb = rp[ww];
        u64 c = ww < 5 ? rp[ww + 1] : 0ull;
        __uint128_t X = (((__uint128_t)bb) << 64) | a;
        X |= X << 1; X |= X << 2; X |= X << 4; X |= X << 8;
        __uint128_t Z = (((__uint128_t)c) << 64) | bb;
        Z |= Z >> 1; Z |= Z >> 2; Z |= Z >> 4; Z |= Z >> 8;
        A[w] = (u64)(X >> 64) | (u64)Z;
    }
    __syncthreads();

    // ---- dilate_v15: A -> Bf ----
    for (int w = t; w < NW; w += 256) {
        int row = div6(w);
        int ww = w - row * 6;
        int lo2 = row - 15 < 0 ? 0 : row - 15;
        int hi2 = row + 15 > nrows - 1 ? nrows - 1 : row + 15;
        u64 acc = 0ull;
        for (int rr = lo2; rr <= hi2; ++rr) acc |= A[rr * 6 + ww];
        Bf[w] = acc;
    }
    __syncthreads();

    // ---- erode_h14: Bf -> A ----
    for (int w = t; w < NW; w += 256) {
        int row = div6(w);
        int ww = w - row * 6;
        const u64* rp = &Bf[row * 6];
        u64 a = ww > 0 ? rp[ww - 1] : ~0ull;
        u64 bb = rp[ww];
        u64 c = ww < 5 ? rp[ww + 1] : ~0ull;
        u64 na = ~a, nb = ~bb, nc = ~c;
        __uint128_t X = (((__uint128_t)nb) << 64) | na;
        X |= X << 1; X |= X << 2; X |= X << 4; X |= X << 7;
        __uint128_t Z = (((__uint128_t)nc) << 64) | nb;
        Z |= Z >> 1; Z |= Z >> 2; Z |= Z >> 4; Z |= Z >> 7;
        A[w] = ~((u64)(X >> 64) | (u64)Z);
    }
    __syncthreads();

    // ---- erode_v14: A -> global, output rows [r0, r0+48) ----
    u64* gout = gout_all + (size_t)b * IMG_WORDS;
    const int base = r0 - w0row;
    for (int w = t; w < SLAB * WPR; w += 256) {
        int lrow = div6(w);
        int ww = w - lrow * 6;
        int lr = base + lrow;
        int lo2 = lr - 14 < 0 ? 0 : lr - 14;
        int hi2 = lr + 14 > nrows - 1 ? nrows - 1 : lr + 14;
        u64 acc = ~0ull;
        for (int rr = lo2; rr <= hi2; ++rr) acc &= A[rr * 6 + ww];
        gout[(size_t)(r0 + lrow) * WPR + ww] = acc;
    }
}

// ---- K3: masked SSIM, CW=2, chunk=27, depth-1 row prefetch ----------------
// grid (3, 7, 128), block 128 (2 waves). Each thread: cols (2p,2p+1), 27
// output rows (33 input rows), rings with static phase index, prefetch of
// row rr+1's X/Y/mask issued before computing row rr (keeps HBM misses in
// flight across the compute burst).
__global__ void __launch_bounds__(128) k_ssim(
    const float* __restrict__ Xg, const float* __restrict__ Yg,
    const float* __restrict__ drg, const u64* __restrict__ Mg,
    float* __restrict__ accum)
{
    const int tx = threadIdx.x & 63;
    const int cz = threadIdx.x >> 6;                  // 0..1
    const int p  = blockIdx.x * 64 + tx;              // pair index
    const int chunk = blockIdx.y * 2 + cz;            // 0..13
    const int b  = blockIdx.z;

    float lsum = 0.0f;
    if (p < 189) {
        const int j  = p * 2;
        const int i0 = chunk * 27;                    // 378 = 14*27 exact
        const float drv = drg[b];
        const float C1q = 1e-4f * drv * drv * 2401.0f;    // C1*49^2
        const float C2q = 9e-4f * drv * drv * 2401.0f;    // C2*49^2
        const float* xr = Xg + (size_t)b * HH * WW_ + (size_t)i0 * WW_ + j;
        const float* yr = Yg + (size_t)b * HH * WW_ + (size_t)i0 * WW_ + j;
        const unsigned* mr = (const unsigned*)Mg + ((size_t)b * HH + i0) * 12 + (j >> 5);
        const int sh32 = j & 31;

        v2 r0[7], r1[7], r2[7], r3[7], r4[7];
        #pragma unroll
        for (int t = 0; t < 7; ++t) {
            r0[t] = 0.f; r1[t] = 0.f; r2[t] = 0.f; r3[t] = 0.f; r4[t] = 0.f;
        }
        v2 s0 = 0.f, s1 = 0.f, s2 = 0.f, s3 = 0.f, s4 = 0.f;

        // preload row 0
        v2 cx0 = *(const v2*)(xr),     cx1 = *(const v2*)(xr + 2);
        v2 cx2 = *(const v2*)(xr + 4), cx3 = *(const v2*)(xr + 6);
        v2 cy0 = *(const v2*)(yr),     cy1 = *(const v2*)(yr + 2);
        v2 cy2 = *(const v2*)(yr + 4), cy3 = *(const v2*)(yr + 6);
        unsigned cm0 = mr[0], cm1 = mr[1];

        for (int bs = 0; bs < 33; bs += 7) {
            #pragma unroll
            for (int ph = 0; ph < 7; ++ph) {
                const int rr = bs + ph;
                if (rr >= 33) break;                  // uniform

                // ---- prefetch row rr+1 ----
                v2 nx0 = 0.f, nx1 = 0.f, nx2 = 0.f, nx3 = 0.f;
                v2 ny0 = 0.f, ny1 = 0.f, ny2 = 0.f, ny3 = 0.f;
                unsigned nm0 = 0u, nm1 = 0u;
                if (rr + 1 < 33) {
                    const float* xn = xr + (size_t)(rr + 1) * WW_;
                    const float* yn = yr + (size_t)(rr + 1) * WW_;
                    nx0 = *(const v2*)(xn);     nx1 = *(const v2*)(xn + 2);
                    nx2 = *(const v2*)(xn + 4); nx3 = *(const v2*)(xn + 6);
                    ny0 = *(const v2*)(yn);     ny1 = *(const v2*)(yn + 2);
                    ny2 = *(const v2*)(yn + 4); ny3 = *(const v2*)(yn + 6);
                    const unsigned* mn = mr + (size_t)(rr + 1) * 12;
                    nm0 = mn[0]; nm1 = mn[1];
                }

                // ---- compute row rr from cur regs ----
                unsigned win8 = __builtin_amdgcn_alignbit(cm1, cm0, sh32) & 0xFFu;
                v2 xa = cx0, xb = cx1, xc = cx2, xd = cx3;
                v2 ya = cy0, yb = cy1, yc = cy2, yd = cy3;

                if (__builtin_expect(__any(win8 != 0xFFu), 0)) {
                    float m0 = (float)( win8       & 1u);
                    float m1 = (float)((win8 >> 1) & 1u);
                    float m2 = (float)((win8 >> 2) & 1u);
                    float m3 = (float)((win8 >> 3) & 1u);
                    float m4 = (float)((win8 >> 4) & 1u);
                    float m5 = (float)((win8 >> 5) & 1u);
                    float m6 = (float)((win8 >> 6) & 1u);
                    float m7 = (float)((win8 >> 7) & 1u);
                    xa.x *= m0; xa.y *= m1; xb.x *= m2; xb.y *= m3;
                    xc.x *= m4; xc.y *= m5; xd.x *= m6; xd.y *= m7;
                    ya.x *= m0; ya.y *= m1; yb.x *= m2; yb.y *= m3;
                    yc.x *= m4; yc.y *= m5; yd.x *= m6; yd.y *= m7;
                }

                v2 xxa = xa * xa, xxb = xb * xb, xxc = xc * xc, xxd = xd * xd;
                v2 yya = ya * ya, yyb = yb * yb, yyc = yc * yc, yyd = yd * yd;
                v2 xya = xa * ya, xyb = xb * yb, xyc = xc * yc, xyd = xd * yd;

                float h;
                h = ((xa.x + xa.y) + (xb.x + xb.y)) + ((xc.x + xc.y) + xd.x);
                v2 hX  = { h, h + xd.y - xa.x };
                h = ((ya.x + ya.y) + (yb.x + yb.y)) + ((yc.x + yc.y) + yd.x);
                v2 hY  = { h, h + yd.y - ya.x };
                h = ((xxa.x + xxa.y) + (xxb.x + xxb.y)) + ((xxc.x + xxc.y) + xxd.x);
                v2 hXX = { h, h + xxd.y - xxa.x };
                h = ((yya.x + yya.y) + (yyb.x + yyb.y)) + ((yyc.x + yyc.y) + yyd.x);
                v2 hYY = { h, h + yyd.y - yya.x };
                h = ((xya.x + xya.y) + (xyb.x + xyb.y)) + ((xyc.x + xyc.y) + xyd.x);
                v2 hXY = { h, h + xyd.y - xya.x };

                v2 o;
                o = r0[ph]; r0[ph] = hX;  s0 += hX  - o;
                o = r1[ph]; r1[ph] = hY;  s1 += hY  - o;
                o = r2[ph]; r2[ph] = hXX; s2 += hXX - o;
                o = r3[ph]; r3[ph] = hYY; s3 += hYY - o;
                o = r4[ph]; r4[ph] = hXY; s4 += hXY - o;

                if (rr >= 6) {
                    v2 t3  = s0 * s1;
                    v2 t12 = s1 * s1 + s0 * s0;
                    v2 A1  = 2.0f * t3 + C1q;
                    v2 u   = 49.0f * s4 - t3;
                    v2 A2  = (2.0f * COVN) * u + C2q;
                    v2 B1  = t12 + C1q;
                    v2 w   = s2 + s3;
                    v2 vsum = 49.0f * w - t12;
                    v2 B2  = COVN * vsum + C2q;
                    v2 num = A1 * A2;
                    v2 den = B1 * B2;
                    float q0 = __builtin_amdgcn_rcpf(den.x);
                    float q1 = __builtin_amdgcn_rcpf(den.y);
                    lsum += num.x * q0 + num.y * q1;
                }

                // ---- rotate ----
                cx0 = nx0; cx1 = nx1; cx2 = nx2; cx3 = nx3;
                cy0 = ny0; cy1 = ny1; cy2 = ny2; cy3 = ny3;
                cm0 = nm0; cm1 = nm1;
            }
        }
    }

    // wave-level reduce (no LDS)
    #pragma unroll
    for (int off = 32; off > 0; off >>= 1) lsum += __shfl_down(lsum, off);
    if (tx == 0) {
        int flat = ((blockIdx.z * 14 + blockIdx.y * 2 + cz) * 3 + blockIdx.x);
        atomicAdd(&accum[flat & 1023], lsum);
    }
}

// ---- K4: finalize -> 1 - sum/N (double accumulate) ------------------------
__global__ void k_final(const float* __restrict__ accum, float* __restrict__ out) {
    __shared__ double sm[256];
    double v = 0.0;
    for (int i = threadIdx.x; i < 1024; i += 256) v += (double)accum[i];
    sm[threadIdx.x] = v;
    __syncthreads();
    #pragma unroll
    for (int off = 128; off > 0; off >>= 1) {
        if (threadIdx.x < off) sm[threadIdx.x] += sm[threadIdx.x + off];
        __syncthreads();
    }
    if (threadIdx.x == 0) {
        out[0] = (float)(1.0 - sm[0] / 18289152.0);   // N = 128*378*378
    }
}

extern "C" void kernel_launch(void* const* d_in, const int* in_sizes, int n_in,
                              void* d_out, int out_size, void* d_ws, size_t ws_size,
                              hipStream_t stream) {
    const float* X  = (const float*)d_in[0];
    const float* Y  = (const float*)d_in[1];
    const float* dr = (const float*)d_in[2];
    float* out = (float*)d_out;

    char* ws = (char*)d_ws;
    float* accum = (float*)ws;                        // 4 KB
    // maskB FIRST so k_ssim's +1-word mask over-read lands in bitsRaw (safe)
    u64* maskB = (u64*)(ws + 4096);                                  // 2.36 MB final mask
    u64* bitsRaw = (u64*)(ws + 4096 + (size_t)(BB * IMG_WORDS) * 8); // 2.36 MB binarized

    k_binarize<<<BIN_BLOCKS, 256, 0, stream>>>(Y, bitsRaw, accum);
    k_morph<<<BB * 8, 256, 0, stream>>>(bitsRaw, maskB);
    dim3 g(3, 7, 128);
    k_ssim<<<g, 128, 0, stream>>>(X, Y, dr, maskB, accum);
    k_final<<<1, 256, 0, stream>>>(accum, out);
}

// Round 6
// 215.898 us; speedup vs baseline: 1.8108x; 1.1082x over previous
//
#include <hip/hip_runtime.h>
#include <stdint.h>

typedef unsigned long long u64;
typedef float v2 __attribute__((ext_vector_type(2)));

#define THRESH_F 5e-5f
#define BB 128
#define HH 384
#define WW_ 384
#define WPR 6                        // u64 words per 384-pixel row
#define IMG_WORDS (HH*WPR)           // 2304
#define OH 378
#define OW 378
#define PIX (BB*HH*WW_)              // 18874368
#define COVN (49.0f/48.0f)

#define SLAB 48                      // output rows per morph block
#define HALO 30                      // morphology chain depth: 1 + 15 + 14
#define MAXROWS (SLAB + 2*HALO)      // 108
#define MAXW (MAXROWS * WPR)         // 648

#define BIN_BLOCKS 1536

// div by 6 via magic, valid for w < 131072
__device__ __forceinline__ int div6(int w) { return (w * 43691) >> 18; }

// ---- K1: binarize Y -> bits. Each wave: 256 contiguous elems per step -----
// lane loads elems base+{0,64,128,192}+lane; 4 ballots give 4 u64 words;
// lanes 0..3 store them contiguously (32B). 12 grid-stride steps, MLP=4.
__global__ void __launch_bounds__(256) k_binarize(const float* __restrict__ Y,
                                                  u64* __restrict__ bits,
                                                  float* __restrict__ accum) {
    if (blockIdx.x == 0) {           // zero accum slots (consumed by k_ssim later)
        for (int i = threadIdx.x; i < 1024; i += 256) accum[i] = 0.f;
    }
    const int lane = threadIdx.x & 63;
    const int wave = (blockIdx.x * 256 + threadIdx.x) >> 6;   // global wave id
    const int nwaves = BIN_BLOCKS * 4;
    const int NSTEP = PIX / 256;                              // 73728
    for (int s = wave; s < NSTEP; s += nwaves) {
        size_t base = (size_t)s * 256 + lane;
        float a0 = Y[base];
        float a1 = Y[base + 64];
        float a2 = Y[base + 128];
        float a3 = Y[base + 192];
        u64 b0 = __ballot(a0 > THRESH_F);
        u64 b1 = __ballot(a1 > THRESH_F);
        u64 b2 = __ballot(a2 > THRESH_F);
        u64 b3 = __ballot(a3 > THRESH_F);
        if (lane < 4) {
            u64 v = (lane == 0) ? b0 : (lane == 1) ? b1 : (lane == 2) ? b2 : b3;
            bits[(size_t)s * 4 + lane] = v;
        }
    }
}

// ---- K2: fused morphology on bits, 8 slabs per image (1024 blocks) --------
__global__ void __launch_bounds__(256) k_morph(const u64* __restrict__ gbits,
                                               u64* __restrict__ gout_all) {
    __shared__ u64 A[MAXW];
    __shared__ u64 Bf[MAXW];
    const int blk = blockIdx.x;
    const int b = blk >> 3;
    const int slab = blk & 7;
    const int r0 = slab * SLAB;
    const int w0row = (r0 - HALO < 0) ? 0 : r0 - HALO;
    int w1row = r0 + SLAB + HALO; if (w1row > HH) w1row = HH;
    const int nrows = w1row - w0row;                  // 78 or 108
    const int NW = nrows * WPR;
    const int t = threadIdx.x;

    const u64* gin = gbits + (size_t)b * IMG_WORDS + (size_t)w0row * WPR;
    for (int w = t; w < NW; w += 256) A[w] = gin[w];
    __syncthreads();

    // ---- erode3: A -> Bf ----
    for (int w = t; w < NW; w += 256) {
        int row = div6(w);
        int ww = w - row * 6;
        int rlo = row > 0 ? row - 1 : row;
        int rhi = row < nrows - 1 ? row + 1 : row;
        u64 res = ~0ull;
        for (int rr = rlo; rr <= rhi; ++rr) {
            const u64* rp = &A[rr * 6];
            u64 a = ww > 0 ? rp[ww - 1] : 0ull;
            u64 bb = rp[ww];
            u64 c = ww < 5 ? rp[ww + 1] : 0ull;
            u64 l  = (bb << 1) | (ww > 0 ? (a >> 63) : 1ull);
            u64 r2 = (bb >> 1) | (ww < 5 ? (c << 63) : (1ull << 63));
            res &= bb & l & r2;
        }
        Bf[w] = res;
    }
    __syncthreads();

    // ---- dilate_h15: Bf -> A ----
    for (int w = t; w < NW; w += 256) {
        int row = div6(w);
        int ww = w - row * 6;
        const u64* rp = &Bf[row * 6];
        u64 a = ww > 0 ? rp[ww - 1] : 0ull;
        u64 bb = rp[ww];
        u64 c = ww < 5 ? rp[ww + 1] : 0ull;
        __uint128_t X = (((__uint128_t)bb) << 64) | a;
        X |= X << 1; X |= X << 2; X |= X << 4; X |= X << 8;
        __uint128_t Z = (((__uint128_t)c) << 64) | bb;
        Z |= Z >> 1; Z |= Z >> 2; Z |= Z >> 4; Z |= Z >> 8;
        A[w] = (u64)(X >> 64) | (u64)Z;
    }
    __syncthreads();

    // ---- dilate_v15: A -> Bf ----
    for (int w = t; w < NW; w += 256) {
        int row = div6(w);
        int ww = w - row * 6;
        int lo2 = row - 15 < 0 ? 0 : row - 15;
        int hi2 = row + 15 > nrows - 1 ? nrows - 1 : row + 15;
        u64 acc = 0ull;
        for (int rr = lo2; rr <= hi2; ++rr) acc |= A[rr * 6 + ww];
        Bf[w] = acc;
    }
    __syncthreads();

    // ---- erode_h14: Bf -> A ----
    for (int w = t; w < NW; w += 256) {
        int row = div6(w);
        int ww = w - row * 6;
        const u64* rp = &Bf[row * 6];
        u64 a = ww > 0 ? rp[ww - 1] : ~0ull;
        u64 bb = rp[ww];
        u64 c = ww < 5 ? rp[ww + 1] : ~0ull;
        u64 na = ~a, nb = ~bb, nc = ~c;
        __uint128_t X = (((__uint128_t)nb) << 64) | na;
        X |= X << 1; X |= X << 2; X |= X << 4; X |= X << 7;
        __uint128_t Z = (((__uint128_t)nc) << 64) | nb;
        Z |= Z >> 1; Z |= Z >> 2; Z |= Z >> 4; Z |= Z >> 7;
        A[w] = ~((u64)(X >> 64) | (u64)Z);
    }
    __syncthreads();

    // ---- erode_v14: A -> global, output rows [r0, r0+48) ----
    u64* gout = gout_all + (size_t)b * IMG_WORDS;
    const int base = r0 - w0row;
    for (int w = t; w < SLAB * WPR; w += 256) {
        int lrow = div6(w);
        int ww = w - lrow * 6;
        int lr = base + lrow;
        int lo2 = lr - 14 < 0 ? 0 : lr - 14;
        int hi2 = lr + 14 > nrows - 1 ? nrows - 1 : lr + 14;
        u64 acc = ~0ull;
        for (int rr = lo2; rr <= hi2; ++rr) acc &= A[rr * 6 + ww];
        gout[(size_t)(r0 + lrow) * WPR + ww] = acc;
    }
}

// ---- K3: masked SSIM, CW=2, chunk=27, DEPTH-2 row pipeline ----------------
// grid (3, 7, 128), block 128. While computing row rr, rows rr+1 and rr+2
// are in flight (2 x ~160 issue-cycles x 3 waves/SIMD covers ~900cyc HBM).
__global__ void __launch_bounds__(128) k_ssim(
    const float* __restrict__ Xg, const float* __restrict__ Yg,
    const float* __restrict__ drg, const u64* __restrict__ Mg,
    float* __restrict__ accum)
{
    const int tx = threadIdx.x & 63;
    const int cz = threadIdx.x >> 6;                  // 0..1
    const int p  = blockIdx.x * 64 + tx;              // pair index
    const int chunk = blockIdx.y * 2 + cz;            // 0..13
    const int b  = blockIdx.z;

    float lsum = 0.0f;
    if (p < 189) {
        const int j  = p * 2;
        const int i0 = chunk * 27;                    // 378 = 14*27 exact
        const float drv = drg[b];
        const float C1q = 1e-4f * drv * drv * 2401.0f;    // C1*49^2
        const float C2q = 9e-4f * drv * drv * 2401.0f;    // C2*49^2
        const float* xr = Xg + (size_t)b * HH * WW_ + (size_t)i0 * WW_ + j;
        const float* yr = Yg + (size_t)b * HH * WW_ + (size_t)i0 * WW_ + j;
        const unsigned* mr = (const unsigned*)Mg + ((size_t)b * HH + i0) * 12 + (j >> 5);
        const int sh32 = j & 31;

        v2 r0[7], r1[7], r2[7], r3[7], r4[7];
        #pragma unroll
        for (int t = 0; t < 7; ++t) {
            r0[t] = 0.f; r1[t] = 0.f; r2[t] = 0.f; r3[t] = 0.f; r4[t] = 0.f;
        }
        v2 s0 = 0.f, s1 = 0.f, s2 = 0.f, s3 = 0.f, s4 = 0.f;

        // pipeline stage A (row rr), stage B (row rr+1)
        v2 ax0 = *(const v2*)(xr),     ax1 = *(const v2*)(xr + 2);
        v2 ax2 = *(const v2*)(xr + 4), ax3 = *(const v2*)(xr + 6);
        v2 ay0 = *(const v2*)(yr),     ay1 = *(const v2*)(yr + 2);
        v2 ay2 = *(const v2*)(yr + 4), ay3 = *(const v2*)(yr + 6);
        unsigned am0 = mr[0], am1 = mr[1];

        const float* xn1 = xr + WW_;
        const float* yn1 = yr + WW_;
        v2 bx0 = *(const v2*)(xn1),     bx1 = *(const v2*)(xn1 + 2);
        v2 bx2 = *(const v2*)(xn1 + 4), bx3 = *(const v2*)(xn1 + 6);
        v2 by0 = *(const v2*)(yn1),     by1 = *(const v2*)(yn1 + 2);
        v2 by2 = *(const v2*)(yn1 + 4), by3 = *(const v2*)(yn1 + 6);
        unsigned bm0 = mr[12], bm1 = mr[13];

        for (int bs = 0; bs < 35; bs += 7) {
            #pragma unroll
            for (int ph = 0; ph < 7; ++ph) {
                const int rr = bs + ph;
                if (rr >= 33) break;                  // uniform

                // ---- prefetch row rr+2 ----
                v2 tx0 = 0.f, tx1 = 0.f, tx2 = 0.f, tx3 = 0.f;
                v2 ty0 = 0.f, ty1 = 0.f, ty2 = 0.f, ty3 = 0.f;
                unsigned tm0 = 0u, tm1 = 0u;
                if (rr + 2 < 33) {
                    const float* xn = xr + (size_t)(rr + 2) * WW_;
                    const float* yn = yr + (size_t)(rr + 2) * WW_;
                    tx0 = *(const v2*)(xn);     tx1 = *(const v2*)(xn + 2);
                    tx2 = *(const v2*)(xn + 4); tx3 = *(const v2*)(xn + 6);
                    ty0 = *(const v2*)(yn);     ty1 = *(const v2*)(yn + 2);
                    ty2 = *(const v2*)(yn + 4); ty3 = *(const v2*)(yn + 6);
                    const unsigned* mn = mr + (size_t)(rr + 2) * 12;
                    tm0 = mn[0]; tm1 = mn[1];
                }

                // ---- compute row rr from stage A ----
                unsigned win8 = __builtin_amdgcn_alignbit(am1, am0, sh32) & 0xFFu;
                v2 xa = ax0, xb = ax1, xc = ax2, xd = ax3;
                v2 ya = ay0, yb = ay1, yc = ay2, yd = ay3;

                if (__builtin_expect(__any(win8 != 0xFFu), 0)) {
                    float m0 = (float)( win8       & 1u);
                    float m1 = (float)((win8 >> 1) & 1u);
                    float m2 = (float)((win8 >> 2) & 1u);
                    float m3 = (float)((win8 >> 3) & 1u);
                    float m4 = (float)((win8 >> 4) & 1u);
                    float m5 = (float)((win8 >> 5) & 1u);
                    float m6 = (float)((win8 >> 6) & 1u);
                    float m7 = (float)((win8 >> 7) & 1u);
                    xa.x *= m0; xa.y *= m1; xb.x *= m2; xb.y *= m3;
                    xc.x *= m4; xc.y *= m5; xd.x *= m6; xd.y *= m7;
                    ya.x *= m0; ya.y *= m1; yb.x *= m2; yb.y *= m3;
                    yc.x *= m4; yc.y *= m5; yd.x *= m6; yd.y *= m7;
                }

                v2 xxa = xa * xa, xxb = xb * xb, xxc = xc * xc, xxd = xd * xd;
                v2 yya = ya * ya, yyb = yb * yb, yyc = yc * yc, yyd = yd * yd;
                v2 xya = xa * ya, xyb = xb * yb, xyc = xc * yc, xyd = xd * yd;

                float h;
                h = ((xa.x + xa.y) + (xb.x + xb.y)) + ((xc.x + xc.y) + xd.x);
                v2 hX  = { h, h + xd.y - xa.x };
                h = ((ya.x + ya.y) + (yb.x + yb.y)) + ((yc.x + yc.y) + yd.x);
                v2 hY  = { h, h + yd.y - ya.x };
                h = ((xxa.x + xxa.y) + (xxb.x + xxb.y)) + ((xxc.x + xxc.y) + xxd.x);
                v2 hXX = { h, h + xxd.y - xxa.x };
                h = ((yya.x + yya.y) + (yyb.x + yyb.y)) + ((yyc.x + yyc.y) + yyd.x);
                v2 hYY = { h, h + yyd.y - yya.x };
                h = ((xya.x + xya.y) + (xyb.x + xyb.y)) + ((xyc.x + xyc.y) + xyd.x);
                v2 hXY = { h, h + xyd.y - xya.x };

                v2 o;
                o = r0[ph]; r0[ph] = hX;  s0 += hX  - o;
                o = r1[ph]; r1[ph] = hY;  s1 += hY  - o;
                o = r2[ph]; r2[ph] = hXX; s2 += hXX - o;
                o = r3[ph]; r3[ph] = hYY; s3 += hYY - o;
                o = r4[ph]; r4[ph] = hXY; s4 += hXY - o;

                if (rr >= 6) {
                    v2 t3  = s0 * s1;
                    v2 t12 = s1 * s1 + s0 * s0;
                    v2 A1  = 2.0f * t3 + C1q;
                    v2 u   = 49.0f * s4 - t3;
                    v2 A2  = (2.0f * COVN) * u + C2q;
                    v2 B1  = t12 + C1q;
                    v2 w   = s2 + s3;
                    v2 vsum = 49.0f * w - t12;
                    v2 B2  = COVN * vsum + C2q;
                    v2 num = A1 * A2;
                    v2 den = B1 * B2;
                    float q0 = __builtin_amdgcn_rcpf(den.x);
                    float q1 = __builtin_amdgcn_rcpf(den.y);
                    lsum += num.x * q0 + num.y * q1;
                }

                // ---- rotate pipeline (renamed by full unroll) ----
                ax0 = bx0; ax1 = bx1; ax2 = bx2; ax3 = bx3;
                ay0 = by0; ay1 = by1; ay2 = by2; ay3 = by3;
                am0 = bm0; am1 = bm1;
                bx0 = tx0; bx1 = tx1; bx2 = tx2; bx3 = tx3;
                by0 = ty0; by1 = ty1; by2 = ty2; by3 = ty3;
                bm0 = tm0; bm1 = tm1;
            }
        }
    }

    // wave-level reduce (no LDS)
    #pragma unroll
    for (int off = 32; off > 0; off >>= 1) lsum += __shfl_down(lsum, off);
    if (tx == 0) {
        int flat = ((blockIdx.z * 14 + blockIdx.y * 2 + cz) * 3 + blockIdx.x);
        atomicAdd(&accum[flat & 1023], lsum);
    }
}

// ---- K4: finalize -> 1 - sum/N (double accumulate) ------------------------
__global__ void k_final(const float* __restrict__ accum, float* __restrict__ out) {
    __shared__ double sm[256];
    double v = 0.0;
    for (int i = threadIdx.x; i < 1024; i += 256) v += (double)accum[i];
    sm[threadIdx.x] = v;
    __syncthreads();
    #pragma unroll
    for (int off = 128; off > 0; off >>= 1) {
        if (threadIdx.x < off) sm[threadIdx.x] += sm[threadIdx.x + off];
        __syncthreads();
    }
    if (threadIdx.x == 0) {
        out[0] = (float)(1.0 - sm[0] / 18289152.0);   // N = 128*378*378
    }
}

extern "C" void kernel_launch(void* const* d_in, const int* in_sizes, int n_in,
                              void* d_out, int out_size, void* d_ws, size_t ws_size,
                              hipStream_t stream) {
    const float* X  = (const float*)d_in[0];
    const float* Y  = (const float*)d_in[1];
    const float* dr = (const float*)d_in[2];
    float* out = (float*)d_out;

    char* ws = (char*)d_ws;
    float* accum = (float*)ws;                        // 4 KB
    // maskB FIRST so k_ssim's +1-word mask over-read lands in bitsRaw (safe)
    u64* maskB = (u64*)(ws + 4096);                                  // 2.36 MB final mask
    u64* bitsRaw = (u64*)(ws + 4096 + (size_t)(BB * IMG_WORDS) * 8); // 2.36 MB binarized

    k_binarize<<<BIN_BLOCKS, 256, 0, stream>>>(Y, bitsRaw, accum);
    k_morph<<<BB * 8, 256, 0, stream>>>(bitsRaw, maskB);
    dim3 g(3, 7, 128);
    k_ssim<<<g, 128, 0, stream>>>(X, Y, dr, maskB, accum);
    k_final<<<1, 256, 0, stream>>>(accum, out);
}